// Round 1
// baseline (936.529 us; speedup 1.0000x reference)
//
#include <hip/hip_runtime.h>
#include <hip/hip_bf16.h>
#include <stdint.h>

// Problem dims
#define M_DIM 8192
#define K_DIM 7168
#define N_DIM 2112          // 1536 + 512 + 64
#define N_PAD 2176          // 17 * 128
#define NQ 1536
#define NKV 512
#define NPE 64
#define NGROUPS 12          // 1536 / 128

// GEMM tiling (m97 structure)
#define TM 128
#define TN 128
#define TK 64

typedef __bf16 bf16x8 __attribute__((ext_vector_type(8)));
typedef float f32x4 __attribute__((ext_vector_type(4)));

__device__ inline unsigned short f32_to_bf16(float f) {
    unsigned int u = __float_as_uint(f);
    u += 0x7fffu + ((u >> 16) & 1u);   // round-to-nearest-even
    return (unsigned short)(u >> 16);
}

// ---------------------------------------------------------------------------
// Kernel 1: A fp32 -> bf16, elementwise, vectorized
// ---------------------------------------------------------------------------
__global__ __launch_bounds__(256) void cvt_a_kernel(
    const float* __restrict__ in, unsigned short* __restrict__ out, int n4)
{
    int idx = blockIdx.x * 256 + threadIdx.x;
    int stride = gridDim.x * 256;
    const float4* in4 = (const float4*)in;
    ushort4* out4 = (ushort4*)out;
    for (int i = idx; i < n4; i += stride) {
        float4 v = in4[i];
        ushort4 o;
        o.x = f32_to_bf16(v.x);
        o.y = f32_to_bf16(v.y);
        o.z = f32_to_bf16(v.z);
        o.w = f32_to_bf16(v.w);
        out4[i] = o;
    }
}

// ---------------------------------------------------------------------------
// Kernel 2: W [K][N] fp32 -> Bt [N_PAD][K] bf16 (tiled transpose + convert)
// grid = (N_DIM/32, K_DIM/32)
// ---------------------------------------------------------------------------
__global__ __launch_bounds__(256) void cvt_bt_kernel(
    const float* __restrict__ B, unsigned short* __restrict__ Bt)
{
    __shared__ float tile[32][33];
    const int n0 = blockIdx.x * 32;
    const int k0 = blockIdx.y * 32;
    const int tx = threadIdx.x & 31;
    const int ty = threadIdx.x >> 5;       // 0..7
#pragma unroll
    for (int i = 0; i < 4; ++i) {
        int kk = ty + i * 8;
        tile[kk][tx] = B[(size_t)(k0 + kk) * N_DIM + n0 + tx];
    }
    __syncthreads();
#pragma unroll
    for (int i = 0; i < 4; ++i) {
        int nn = ty + i * 8;
        Bt[(size_t)(n0 + nn) * K_DIM + k0 + tx] = f32_to_bf16(tile[tx][nn]);
    }
}

// ---------------------------------------------------------------------------
// Kernel 3: bf16 MFMA GEMM, C[M][N_PAD] fp32 = A[M][K] * Bt[N_PAD][K]^T
// 128x128 tile, BK=64, 256 threads (4 waves, 2x2), global_load_lds width 16.
// ---------------------------------------------------------------------------
__global__ __launch_bounds__(256) void gemm_bf16_kernel(
    const unsigned short* __restrict__ A,
    const unsigned short* __restrict__ Bt,
    float* __restrict__ C)
{
    __shared__ unsigned short smA[TM * TK];   // [128 rows][64 k], 16 KiB
    __shared__ unsigned short smB[TN * TK];   // [128 n]   [64 k], 16 KiB

    const int t = threadIdx.x;
    const int lane = t & 63;
    const int wave = t >> 6;
    const int m0 = blockIdx.y * TM;
    const int n0 = blockIdx.x * TN;

    const int wr = wave >> 1;        // 0..1
    const int wc = wave & 1;         // 0..1
    const int mrow = lane & 15;      // fragment row/col within 16
    const int koff = (lane >> 4) * 8;

    // staging: chunk = wave*4+i covers 1024 B of LDS; lane -> +16 B
    const int ldRow = lane >> 3;          // 0..7 within chunk
    const int ldK   = (lane & 7) * 8;     // 0..56

    f32x4 acc[4][4];
#pragma unroll
    for (int i = 0; i < 4; ++i)
#pragma unroll
        for (int j = 0; j < 4; ++j)
            acc[i][j] = (f32x4)0.0f;

    for (int kt = 0; kt < K_DIM; kt += TK) {
#pragma unroll
        for (int i = 0; i < 4; ++i) {
            const int c = wave * 4 + i;          // 0..15
            const int row = c * 8 + ldRow;       // 0..127
            const unsigned short* ga = A  + (size_t)(m0 + row) * K_DIM + kt + ldK;
            const unsigned short* gb = Bt + (size_t)(n0 + row) * K_DIM + kt + ldK;
            __builtin_amdgcn_global_load_lds(
                (const __attribute__((address_space(1))) unsigned int*)ga,
                (__attribute__((address_space(3))) unsigned int*)(smA + c * 512),
                16, 0, 0);
            __builtin_amdgcn_global_load_lds(
                (const __attribute__((address_space(1))) unsigned int*)gb,
                (__attribute__((address_space(3))) unsigned int*)(smB + c * 512),
                16, 0, 0);
        }
        __syncthreads();

#pragma unroll
        for (int ks = 0; ks < 2; ++ks) {
            bf16x8 afr[4], bfr[4];
#pragma unroll
            for (int i = 0; i < 4; ++i)
                afr[i] = *reinterpret_cast<const bf16x8*>(
                    &smA[(wr * 64 + i * 16 + mrow) * TK + ks * 32 + koff]);
#pragma unroll
            for (int j = 0; j < 4; ++j)
                bfr[j] = *reinterpret_cast<const bf16x8*>(
                    &smB[(wc * 64 + j * 16 + mrow) * TK + ks * 32 + koff]);
#pragma unroll
            for (int i = 0; i < 4; ++i)
#pragma unroll
                for (int j = 0; j < 4; ++j)
                    acc[i][j] = __builtin_amdgcn_mfma_f32_16x16x32_bf16(
                        afr[i], bfr[j], acc[i][j], 0, 0, 0);
        }
        __syncthreads();
    }

    // Epilogue: C/D layout col = lane&15, row = (lane>>4)*4 + v  (m89/m91)
    const int crow = (lane >> 4) * 4;
    const int ccol = lane & 15;
#pragma unroll
    for (int i = 0; i < 4; ++i) {
#pragma unroll
        for (int j = 0; j < 4; ++j) {
            const int gm = m0 + wr * 64 + i * 16 + crow;
            const int gn = n0 + wc * 64 + j * 16 + ccol;
            float* cp = C + (size_t)gm * N_PAD + gn;
#pragma unroll
            for (int v = 0; v < 4; ++v)
                cp[(size_t)v * N_PAD] = acc[i][j][v];
        }
    }
}

// ---------------------------------------------------------------------------
// Kernel 4: per-row epilogue: RMSNorm(q) + group quant, RMSNorm(kv), k_pe copy
// one block (256 threads) per row
// ---------------------------------------------------------------------------
__global__ __launch_bounds__(256) void epilogue_kernel(
    const float* __restrict__ C,
    const float* __restrict__ qw,
    const float* __restrict__ kvw,
    float* __restrict__ out)
{
    const size_t OQ   = 0;
    const size_t OS   = (size_t)M_DIM * NQ;
    const size_t OKV  = OS + (size_t)M_DIM * NGROUPS;
    const size_t OKPE = OKV + (size_t)M_DIM * NKV;

    const int row = blockIdx.x;
    const float* c = C + (size_t)row * N_PAD;
    const int t = threadIdx.x;
    const int lane = t & 63;
    const int wv = t >> 6;

    __shared__ float red1[4], red2[4];
    __shared__ int smax[NGROUPS];
    __shared__ float sscale[NGROUPS];
    if (t < NGROUPS) smax[t] = 0;

    float qv[6];
    float ssq = 0.f;
#pragma unroll
    for (int i = 0; i < 6; ++i) {
        qv[i] = c[t + i * 256];
        ssq += qv[i] * qv[i];
    }
    float kva = c[NQ + t];
    float kvb = c[NQ + 256 + t];
    float ssk = kva * kva + kvb * kvb;

#pragma unroll
    for (int off = 32; off; off >>= 1) {
        ssq += __shfl_down(ssq, off);
        ssk += __shfl_down(ssk, off);
    }
    if (lane == 0) { red1[wv] = ssq; red2[wv] = ssk; }
    __syncthreads();
    ssq = red1[0] + red1[1] + red1[2] + red1[3];
    ssk = red2[0] + red2[1] + red2[2] + red2[3];

    const float rsq = rsqrtf(ssq * (1.0f / NQ) + 1e-6f);
    const float rsk = rsqrtf(ssk * (1.0f / NKV) + 1e-6f);

    float qn[6];
#pragma unroll
    for (int i = 0; i < 6; ++i) {
        const int col = t + i * 256;
        qn[i] = qv[i] * rsq * qw[col];
        atomicMax(&smax[col >> 7], __float_as_int(fabsf(qn[i])));
    }
    __syncthreads();
    if (t < NGROUPS) {
        const float s = fmaxf(__int_as_float(smax[t]) * (1.0f / 448.0f), 1e-12f);
        sscale[t] = s;
        out[OS + (size_t)row * NGROUPS + t] = s;
    }
    __syncthreads();
#pragma unroll
    for (int i = 0; i < 6; ++i) {
        const int col = t + i * 256;
        out[OQ + (size_t)row * NQ + col] = qn[i] / sscale[col >> 7];
    }
    out[OKV + (size_t)row * NKV + t]       = kva * rsk * kvw[t];
    out[OKV + (size_t)row * NKV + t + 256] = kvb * rsk * kvw[t + 256];
    if (t < NPE) out[OKPE + (size_t)row * NPE + t] = c[2048 + t];
}

// ---------------------------------------------------------------------------
extern "C" void kernel_launch(void* const* d_in, const int* in_sizes, int n_in,
                              void* d_out, int out_size, void* d_ws, size_t ws_size,
                              hipStream_t stream)
{
    const float* hs  = (const float*)d_in[0];   // [8192][7168]
    const float* w   = (const float*)d_in[1];   // [7168][2112]
    const float* qw  = (const float*)d_in[2];   // [1536]
    const float* kvw = (const float*)d_in[3];   // [512]
    float* out = (float*)d_out;

    char* ws = (char*)d_ws;
    const size_t A_BYTES  = (size_t)M_DIM * K_DIM * 2;   // 117,440,512
    const size_t BT_BYTES = (size_t)N_PAD * K_DIM * 2;   //  31,195,136
    unsigned short* Abf = (unsigned short*)ws;
    unsigned short* Bt  = (unsigned short*)(ws + A_BYTES);
    float* C            = (float*)(ws + A_BYTES + BT_BYTES);

    // 1) A fp32 -> bf16
    cvt_a_kernel<<<4096, 256, 0, stream>>>(hs, Abf, (M_DIM * K_DIM) / 4);

    // 2) W -> Bt (transpose + convert)
    dim3 gt(N_DIM / 32, K_DIM / 32);
    cvt_bt_kernel<<<gt, 256, 0, stream>>>(w, Bt);

    // 3) GEMM
    dim3 gg(N_PAD / TN, M_DIM / TM);   // (17, 64)
    gemm_bf16_kernel<<<gg, 256, 0, stream>>>(Abf, Bt, C);

    // 4) epilogue
    epilogue_kernel<<<M_DIM, 256, 0, stream>>>(C, qw, kvw, out);
}

// Round 2
// 820.149 us; speedup vs baseline: 1.1419x; 1.1419x over previous
//
#include <hip/hip_runtime.h>
#include <hip/hip_bf16.h>
#include <stdint.h>

// Problem dims
#define M_DIM 8192
#define K_DIM 7168
#define N_DIM 2112          // 1536 + 512 + 64
#define N_PAD 2176          // 17 * 128
#define NQ 1536
#define NKV 512
#define NPE 64
#define NGROUPS 12          // 1536 / 128

// GEMM tiling (m97 structure)
#define TM 128
#define TN 128
#define TK 64

typedef __bf16 bf16x8 __attribute__((ext_vector_type(8)));
typedef float f32x4 __attribute__((ext_vector_type(4)));
typedef unsigned short ushort8 __attribute__((ext_vector_type(8)));

__device__ inline unsigned short f32_to_bf16(float f) {
    unsigned int u = __float_as_uint(f);
    u += 0x7fffu + ((u >> 16) & 1u);   // round-to-nearest-even
    return (unsigned short)(u >> 16);
}

// ---------------------------------------------------------------------------
// Kernel 1: A fp32 -> bf16, elementwise, vectorized
// ---------------------------------------------------------------------------
__global__ __launch_bounds__(256) void cvt_a_kernel(
    const float* __restrict__ in, unsigned short* __restrict__ out, int n4)
{
    int idx = blockIdx.x * 256 + threadIdx.x;
    int stride = gridDim.x * 256;
    const float4* in4 = (const float4*)in;
    ushort4* out4 = (ushort4*)out;
    for (int i = idx; i < n4; i += stride) {
        float4 v = in4[i];
        ushort4 o;
        o.x = f32_to_bf16(v.x);
        o.y = f32_to_bf16(v.y);
        o.z = f32_to_bf16(v.z);
        o.w = f32_to_bf16(v.w);
        out4[i] = o;
    }
}

// ---------------------------------------------------------------------------
// Kernel 2: W [K][N] fp32 -> Bt [N_PAD][K] bf16 (tiled transpose + convert)
// 64(k) x 32(n) tile; 16B ushort8 writes. grid = (N_DIM/32, K_DIM/64)
// ---------------------------------------------------------------------------
__global__ __launch_bounds__(256) void cvt_bt_kernel(
    const float* __restrict__ B, unsigned short* __restrict__ Bt)
{
    __shared__ float tile[64][33];
    const int n0 = blockIdx.x * 32;
    const int k0 = blockIdx.y * 64;
    const int t = threadIdx.x;
    const int tx = t & 31;         // n within tile
    const int ty = t >> 5;         // 0..7
#pragma unroll
    for (int i = 0; i < 8; ++i) {
        int kk = ty + i * 8;
        tile[kk][tx] = B[(size_t)(k0 + kk) * N_DIM + n0 + tx];
    }
    __syncthreads();
    const int n_idx = t >> 3;        // 0..31
    const int k8 = (t & 7) * 8;      // 0..56
    ushort8 o;
#pragma unroll
    for (int j = 0; j < 8; ++j)
        o[j] = f32_to_bf16(tile[k8 + j][n_idx]);
    *reinterpret_cast<ushort8*>(&Bt[(size_t)(n0 + n_idx) * K_DIM + k0 + k8]) = o;
}

// ---------------------------------------------------------------------------
// Kernel 3: bf16 MFMA GEMM, C[M][N_PAD] fp32 = A[M][K] * Bt[N_PAD][K]^T
// 128x128 tile, BK=64, 256 threads (4 waves, 2x2), global_load_lds width 16.
// XOR-swizzled LDS: (row, kblock) stored at row*128B + (kblock ^ (row&7))*16B.
// Grid: x = M tiles (fastest) so all N-consumers of one A tile land on the
// same XCD; y = N tiles.
// ---------------------------------------------------------------------------
__global__ __launch_bounds__(256) void gemm_bf16_kernel(
    const unsigned short* __restrict__ A,
    const unsigned short* __restrict__ Bt,
    float* __restrict__ C)
{
    __shared__ unsigned short smA[TM * TK];   // 16 KiB
    __shared__ unsigned short smB[TN * TK];   // 16 KiB

    const int t = threadIdx.x;
    const int lane = t & 63;
    const int wave = t >> 6;
    const int m0 = blockIdx.x * TM;
    const int n0 = blockIdx.y * TN;

    const int wr = wave >> 1;        // 0..1
    const int wc = wave & 1;         // 0..1
    const int mrow = lane & 15;      // fragment row within 16
    const int r7 = lane & 7;         // row&7 for swizzle on read side

    // staging: chunk c = wave*4+i covers rows c*8..c*8+7 (1024 B of LDS);
    // lane's physical slot = row_in_chunk (lane>>3), phys kblock (lane&7).
    // It must hold logical kblock (lane&7) ^ (lane>>3).
    const int ldRow = lane >> 3;                    // 0..7 within chunk
    const int ldK   = ((lane & 7) ^ ldRow) * 8;     // swizzled logical kblock, in shorts

    f32x4 acc[4][4];
#pragma unroll
    for (int i = 0; i < 4; ++i)
#pragma unroll
        for (int j = 0; j < 4; ++j)
            acc[i][j] = (f32x4)0.0f;

    for (int kt = 0; kt < K_DIM; kt += TK) {
#pragma unroll
        for (int i = 0; i < 4; ++i) {
            const int c = wave * 4 + i;          // 0..15
            const int row = c * 8 + ldRow;       // 0..127
            const unsigned short* ga = A  + (size_t)(m0 + row) * K_DIM + kt + ldK;
            const unsigned short* gb = Bt + (size_t)(n0 + row) * K_DIM + kt + ldK;
            __builtin_amdgcn_global_load_lds(
                (const __attribute__((address_space(1))) unsigned int*)ga,
                (__attribute__((address_space(3))) unsigned int*)(smA + c * 512),
                16, 0, 0);
            __builtin_amdgcn_global_load_lds(
                (const __attribute__((address_space(1))) unsigned int*)gb,
                (__attribute__((address_space(3))) unsigned int*)(smB + c * 512),
                16, 0, 0);
        }
        __syncthreads();

#pragma unroll
        for (int ks = 0; ks < 2; ++ks) {
            const int lb = ks * 4 + (lane >> 4);     // logical kblock 0..7
            bf16x8 afr[4], bfr[4];
#pragma unroll
            for (int i = 0; i < 4; ++i) {
                const int r = wr * 64 + i * 16 + mrow;
                afr[i] = *reinterpret_cast<const bf16x8*>(
                    &smA[r * TK + ((lb ^ r7) * 8)]);
            }
#pragma unroll
            for (int j = 0; j < 4; ++j) {
                const int r = wc * 64 + j * 16 + mrow;
                bfr[j] = *reinterpret_cast<const bf16x8*>(
                    &smB[r * TK + ((lb ^ r7) * 8)]);
            }
#pragma unroll
            for (int i = 0; i < 4; ++i)
#pragma unroll
                for (int j = 0; j < 4; ++j)
                    acc[i][j] = __builtin_amdgcn_mfma_f32_16x16x32_bf16(
                        afr[i], bfr[j], acc[i][j], 0, 0, 0);
        }
        __syncthreads();
    }

    // Epilogue: C/D layout col = lane&15, row = (lane>>4)*4 + v  (m89/m91)
    const int crow = (lane >> 4) * 4;
    const int ccol = lane & 15;
#pragma unroll
    for (int i = 0; i < 4; ++i) {
#pragma unroll
        for (int j = 0; j < 4; ++j) {
            const int gm = m0 + wr * 64 + i * 16 + crow;
            const int gn = n0 + wc * 64 + j * 16 + ccol;
            float* cp = C + (size_t)gm * N_PAD + gn;
#pragma unroll
            for (int v = 0; v < 4; ++v)
                cp[(size_t)v * N_PAD] = acc[i][j][v];
        }
    }
}

// ---------------------------------------------------------------------------
// Kernel 4: per-row epilogue: RMSNorm(q) + group quant, RMSNorm(kv), k_pe copy
// one block (256 threads) per row. No atomics: group g = 2i + (t>>7) maps
// onto wave pairs; shuffle-max per wave, combine via LDS.
// ---------------------------------------------------------------------------
__global__ __launch_bounds__(256) void epilogue_kernel(
    const float* __restrict__ C,
    const float* __restrict__ qw,
    const float* __restrict__ kvw,
    float* __restrict__ out)
{
    const size_t OQ   = 0;
    const size_t OS   = (size_t)M_DIM * NQ;
    const size_t OKV  = OS + (size_t)M_DIM * NGROUPS;
    const size_t OKPE = OKV + (size_t)M_DIM * NKV;

    const int row = blockIdx.x;
    const float* c = C + (size_t)row * N_PAD;
    const int t = threadIdx.x;
    const int lane = t & 63;
    const int wv = t >> 6;

    __shared__ float red1[4], red2[4];
    __shared__ float wamax[4][6];
    __shared__ float srecip[NGROUPS];

    float qv[6];
    float ssq = 0.f;
#pragma unroll
    for (int i = 0; i < 6; ++i) {
        qv[i] = c[t + i * 256];
        ssq += qv[i] * qv[i];
    }
    float kva = c[NQ + t];
    float kvb = c[NQ + 256 + t];
    float ssk = kva * kva + kvb * kvb;

#pragma unroll
    for (int off = 32; off; off >>= 1) {
        ssq += __shfl_down(ssq, off);
        ssk += __shfl_down(ssk, off);
    }
    if (lane == 0) { red1[wv] = ssq; red2[wv] = ssk; }
    __syncthreads();
    ssq = red1[0] + red1[1] + red1[2] + red1[3];
    ssk = red2[0] + red2[1] + red2[2] + red2[3];

    const float rsq = rsqrtf(ssq * (1.0f / NQ) + 1e-6f);
    const float rsk = rsqrtf(ssk * (1.0f / NKV) + 1e-6f);

    float qn[6], am[6];
#pragma unroll
    for (int i = 0; i < 6; ++i) {
        const int col = t + i * 256;
        qn[i] = qv[i] * rsq * qw[col];
        am[i] = fabsf(qn[i]);
    }
#pragma unroll
    for (int off = 32; off; off >>= 1)
#pragma unroll
        for (int i = 0; i < 6; ++i)
            am[i] = fmaxf(am[i], __shfl_down(am[i], off));
    if (lane == 0)
#pragma unroll
        for (int i = 0; i < 6; ++i) wamax[wv][i] = am[i];
    __syncthreads();

    if (t < NGROUPS) {
        const int i = t >> 1, h = t & 1;
        const float a = fmaxf(wamax[2 * h][i], wamax[2 * h + 1][i]);
        const float s = fmaxf(a * (1.0f / 448.0f), 1e-12f);
        out[OS + (size_t)row * NGROUPS + t] = s;
        srecip[t] = 1.0f / s;
    }
    __syncthreads();

#pragma unroll
    for (int i = 0; i < 6; ++i) {
        const int g = (t >> 7) + 2 * i;
        out[OQ + (size_t)row * NQ + t + i * 256] = qn[i] * srecip[g];
    }
    out[OKV + (size_t)row * NKV + t]       = kva * rsk * kvw[t];
    out[OKV + (size_t)row * NKV + t + 256] = kvb * rsk * kvw[t + 256];
    if (t < NPE) out[OKPE + (size_t)row * NPE + t] = c[2048 + t];
}

// ---------------------------------------------------------------------------
extern "C" void kernel_launch(void* const* d_in, const int* in_sizes, int n_in,
                              void* d_out, int out_size, void* d_ws, size_t ws_size,
                              hipStream_t stream)
{
    const float* hs  = (const float*)d_in[0];   // [8192][7168]
    const float* w   = (const float*)d_in[1];   // [7168][2112]
    const float* qw  = (const float*)d_in[2];   // [1536]
    const float* kvw = (const float*)d_in[3];   // [512]
    float* out = (float*)d_out;

    char* ws = (char*)d_ws;
    const size_t A_BYTES  = (size_t)M_DIM * K_DIM * 2;   // 117,440,512
    const size_t BT_BYTES = (size_t)N_PAD * K_DIM * 2;   //  31,195,136
    unsigned short* Abf = (unsigned short*)ws;
    unsigned short* Bt  = (unsigned short*)(ws + A_BYTES);
    float* C            = (float*)(ws + A_BYTES + BT_BYTES);

    // 1) A fp32 -> bf16
    cvt_a_kernel<<<4096, 256, 0, stream>>>(hs, Abf, (M_DIM * K_DIM) / 4);

    // 2) W -> Bt (transpose + convert)
    dim3 gt(N_DIM / 32, K_DIM / 64);
    cvt_bt_kernel<<<gt, 256, 0, stream>>>(w, Bt);

    // 3) GEMM  (x = M tiles fastest for XCD-local A reuse)
    dim3 gg(M_DIM / TM, N_PAD / TN);   // (64, 17)
    gemm_bf16_kernel<<<gg, 256, 0, stream>>>(Abf, Bt, C);

    // 4) epilogue
    epilogue_kernel<<<M_DIM, 256, 0, stream>>>(C, qw, kvw, out);
}

// Round 3
// 681.730 us; speedup vs baseline: 1.3738x; 1.2030x over previous
//
#include <hip/hip_runtime.h>
#include <hip/hip_bf16.h>
#include <stdint.h>

// Problem dims
#define M_DIM 8192
#define K_DIM 7168
#define N_DIM 2112          // 1536 + 512 + 64
#define N_PAD 2176          // 17 * 128
#define NQ 1536
#define NKV 512
#define NPE 64
#define NGROUPS 12          // 1536 / 128

// GEMM tiling (m97 structure) + split-K
#define TM 128
#define TN 128
#define TK 64
#define SPLITK 2
#define KHALF (K_DIM / SPLITK)   // 3584

typedef __bf16 bf16x8 __attribute__((ext_vector_type(8)));
typedef float f32x4 __attribute__((ext_vector_type(4)));
typedef unsigned short ushort8 __attribute__((ext_vector_type(8)));

__device__ inline unsigned short f32_to_bf16(float f) {
    unsigned int u = __float_as_uint(f);
    u += 0x7fffu + ((u >> 16) & 1u);   // round-to-nearest-even
    return (unsigned short)(u >> 16);
}

// ---------------------------------------------------------------------------
// Kernel 1: A fp32 -> bf16, elementwise, vectorized
// ---------------------------------------------------------------------------
__global__ __launch_bounds__(256) void cvt_a_kernel(
    const float* __restrict__ in, unsigned short* __restrict__ out, int n4)
{
    int idx = blockIdx.x * 256 + threadIdx.x;
    int stride = gridDim.x * 256;
    const float4* in4 = (const float4*)in;
    ushort4* out4 = (ushort4*)out;
    for (int i = idx; i < n4; i += stride) {
        float4 v = in4[i];
        ushort4 o;
        o.x = f32_to_bf16(v.x);
        o.y = f32_to_bf16(v.y);
        o.z = f32_to_bf16(v.z);
        o.w = f32_to_bf16(v.w);
        out4[i] = o;
    }
}

// ---------------------------------------------------------------------------
// Kernel 2: W [K][N] fp32 -> Bt [N_PAD][K] bf16 (tiled transpose + convert)
// 64(k) x 32(n) tile; 16B ushort8 writes. grid = (N_DIM/32, K_DIM/64)
// ---------------------------------------------------------------------------
__global__ __launch_bounds__(256) void cvt_bt_kernel(
    const float* __restrict__ B, unsigned short* __restrict__ Bt)
{
    __shared__ float tile[64][33];
    const int n0 = blockIdx.x * 32;
    const int k0 = blockIdx.y * 64;
    const int t = threadIdx.x;
    const int tx = t & 31;         // n within tile
    const int ty = t >> 5;         // 0..7
#pragma unroll
    for (int i = 0; i < 8; ++i) {
        int kk = ty + i * 8;
        tile[kk][tx] = B[(size_t)(k0 + kk) * N_DIM + n0 + tx];
    }
    __syncthreads();
    const int n_idx = t >> 3;        // 0..31
    const int k8 = (t & 7) * 8;      // 0..56
    ushort8 o;
#pragma unroll
    for (int j = 0; j < 8; ++j)
        o[j] = f32_to_bf16(tile[k8 + j][n_idx]);
    *reinterpret_cast<ushort8*>(&Bt[(size_t)(n0 + n_idx) * K_DIM + k0 + k8]) = o;
}

// ---------------------------------------------------------------------------
// Kernel 3: bf16 MFMA GEMM with split-K=2.
// C_z[M][N_PAD] (bf16) = A[M][kt-half z] * Bt[N_PAD][kt-half z]^T
// 128x128 tile, BK=64, 256 threads (4 waves, 2x2), global_load_lds width 16.
// XOR-swizzled LDS: (row, kblock) stored at row*128B + (kblock ^ (row&7))*16B.
// Grid: x = M tiles (fastest, XCD-exclusive A stripes), y = N tiles, z = K half.
// ---------------------------------------------------------------------------
__global__ __launch_bounds__(256) void gemm_bf16_kernel(
    const unsigned short* __restrict__ A,
    const unsigned short* __restrict__ Bt,
    unsigned short* __restrict__ C)       // [SPLITK][M][N_PAD] bf16
{
    __shared__ unsigned short smA[TM * TK];   // 16 KiB
    __shared__ unsigned short smB[TN * TK];   // 16 KiB

    const int t = threadIdx.x;
    const int lane = t & 63;
    const int wave = t >> 6;
    const int m0 = blockIdx.x * TM;
    const int n0 = blockIdx.y * TN;
    const int kbase = blockIdx.z * KHALF;

    const int wr = wave >> 1;        // 0..1
    const int wc = wave & 1;         // 0..1
    const int mrow = lane & 15;      // fragment row within 16
    const int r7 = lane & 7;         // row&7 for swizzle on read side

    const int ldRow = lane >> 3;                    // 0..7 within chunk
    const int ldK   = ((lane & 7) ^ ldRow) * 8;     // swizzled logical kblock, in shorts

    f32x4 acc[4][4];
#pragma unroll
    for (int i = 0; i < 4; ++i)
#pragma unroll
        for (int j = 0; j < 4; ++j)
            acc[i][j] = (f32x4)0.0f;

    for (int kt = kbase; kt < kbase + KHALF; kt += TK) {
#pragma unroll
        for (int i = 0; i < 4; ++i) {
            const int c = wave * 4 + i;          // 0..15
            const int row = c * 8 + ldRow;       // 0..127
            const unsigned short* ga = A  + (size_t)(m0 + row) * K_DIM + kt + ldK;
            const unsigned short* gb = Bt + (size_t)(n0 + row) * K_DIM + kt + ldK;
            __builtin_amdgcn_global_load_lds(
                (const __attribute__((address_space(1))) unsigned int*)ga,
                (__attribute__((address_space(3))) unsigned int*)(smA + c * 512),
                16, 0, 0);
            __builtin_amdgcn_global_load_lds(
                (const __attribute__((address_space(1))) unsigned int*)gb,
                (__attribute__((address_space(3))) unsigned int*)(smB + c * 512),
                16, 0, 0);
        }
        __syncthreads();

#pragma unroll
        for (int ks = 0; ks < 2; ++ks) {
            const int lb = ks * 4 + (lane >> 4);     // logical kblock 0..7
            bf16x8 afr[4], bfr[4];
#pragma unroll
            for (int i = 0; i < 4; ++i) {
                const int r = wr * 64 + i * 16 + mrow;
                afr[i] = *reinterpret_cast<const bf16x8*>(
                    &smA[r * TK + ((lb ^ r7) * 8)]);
            }
#pragma unroll
            for (int j = 0; j < 4; ++j) {
                const int r = wc * 64 + j * 16 + mrow;
                bfr[j] = *reinterpret_cast<const bf16x8*>(
                    &smB[r * TK + ((lb ^ r7) * 8)]);
            }
#pragma unroll
            for (int i = 0; i < 4; ++i)
#pragma unroll
                for (int j = 0; j < 4; ++j)
                    acc[i][j] = __builtin_amdgcn_mfma_f32_16x16x32_bf16(
                        afr[i], bfr[j], acc[i][j], 0, 0, 0);
        }
        __syncthreads();
    }

    // Epilogue: C/D layout col = lane&15, row = (lane>>4)*4 + v  (m89/m91)
    unsigned short* Cz = C + (size_t)blockIdx.z * M_DIM * N_PAD;
    const int crow = (lane >> 4) * 4;
    const int ccol = lane & 15;
#pragma unroll
    for (int i = 0; i < 4; ++i) {
#pragma unroll
        for (int j = 0; j < 4; ++j) {
            const int gm = m0 + wr * 64 + i * 16 + crow;
            const int gn = n0 + wc * 64 + j * 16 + ccol;
            unsigned short* cp = Cz + (size_t)gm * N_PAD + gn;
#pragma unroll
            for (int v = 0; v < 4; ++v)
                cp[(size_t)v * N_PAD] = f32_to_bf16(acc[i][j][v]);
        }
    }
}

// ---------------------------------------------------------------------------
// Kernel 4: per-row epilogue. Reads both split-K bf16 halves (packed as uint),
// sums in fp32, RMSNorm(q)+group quant, RMSNorm(kv), k_pe.
// One block (256 threads) per row. Each quant group (128 cols) == exactly the
// 64 lanes of one wave at one column-chunk -> pure shuffle-max, no LDS.
// ---------------------------------------------------------------------------
__global__ __launch_bounds__(256) void epilogue_kernel(
    const unsigned short* __restrict__ C0,
    const unsigned short* __restrict__ C1,
    const float* __restrict__ qw,
    const float* __restrict__ kvw,
    float* __restrict__ out)
{
    const size_t OQ   = 0;
    const size_t OS   = (size_t)M_DIM * NQ;
    const size_t OKV  = OS + (size_t)M_DIM * NGROUPS;
    const size_t OKPE = OKV + (size_t)M_DIM * NKV;

    const int row = blockIdx.x;
    const unsigned int* c0 = (const unsigned int*)(C0 + (size_t)row * N_PAD);
    const unsigned int* c1 = (const unsigned int*)(C1 + (size_t)row * N_PAD);
    const int t = threadIdx.x;
    const int lane = t & 63;
    const int wv = t >> 6;

    __shared__ float red1[4], red2[4];

    // q: pair index colp = t + i*256 -> cols 2*colp, 2*colp+1; group = i*4+wv
    float qlo[3], qhi[3];
    float ssq = 0.f;
#pragma unroll
    for (int i = 0; i < 3; ++i) {
        const unsigned int a = c0[t + i * 256];
        const unsigned int b = c1[t + i * 256];
        const float lo = __uint_as_float(a << 16) + __uint_as_float(b << 16);
        const float hi = __uint_as_float(a & 0xffff0000u) + __uint_as_float(b & 0xffff0000u);
        qlo[i] = lo; qhi[i] = hi;
        ssq += lo * lo + hi * hi;
    }
    const unsigned int ka = c0[768 + t];
    const unsigned int kb = c1[768 + t];
    const float klo = __uint_as_float(ka << 16) + __uint_as_float(kb << 16);
    const float khi = __uint_as_float(ka & 0xffff0000u) + __uint_as_float(kb & 0xffff0000u);
    float ssk = klo * klo + khi * khi;

#pragma unroll
    for (int off = 32; off; off >>= 1) {
        ssq += __shfl_down(ssq, off);
        ssk += __shfl_down(ssk, off);
    }
    if (lane == 0) { red1[wv] = ssq; red2[wv] = ssk; }
    __syncthreads();
    ssq = red1[0] + red1[1] + red1[2] + red1[3];
    ssk = red2[0] + red2[1] + red2[2] + red2[3];

    const float rsq = rsqrtf(ssq * (1.0f / NQ) + 1e-6f);
    const float rsk = rsqrtf(ssk * (1.0f / NKV) + 1e-6f);

    const float2* qw2  = (const float2*)qw;
    const float2* kvw2 = (const float2*)kvw;

#pragma unroll
    for (int i = 0; i < 3; ++i) {
        const int colp = t + i * 256;
        const float2 w2 = qw2[colp];
        const float a = qlo[i] * rsq * w2.x;
        const float b = qhi[i] * rsq * w2.y;
        float am = fmaxf(fabsf(a), fabsf(b));
#pragma unroll
        for (int off = 32; off; off >>= 1)
            am = fmaxf(am, __shfl_down(am, off));
        am = __shfl(am, 0);
        const float s = fmaxf(am * (1.0f / 448.0f), 1e-12f);
        if (lane == 0) out[OS + (size_t)row * NGROUPS + i * 4 + wv] = s;
        const float rs = 1.0f / s;
        ((float2*)(out + OQ + (size_t)row * NQ))[colp] = make_float2(a * rs, b * rs);
    }

    const float2 kw2 = kvw2[t];
    ((float2*)(out + OKV + (size_t)row * NKV))[t] =
        make_float2(klo * rsk * kw2.x, khi * rsk * kw2.y);

    if (t < NPE / 2) {
        const unsigned int pa = c0[1024 + t];
        const unsigned int pb = c1[1024 + t];
        ((float2*)(out + OKPE + (size_t)row * NPE))[t] = make_float2(
            __uint_as_float(pa << 16) + __uint_as_float(pb << 16),
            __uint_as_float(pa & 0xffff0000u) + __uint_as_float(pb & 0xffff0000u));
    }
}

// ---------------------------------------------------------------------------
extern "C" void kernel_launch(void* const* d_in, const int* in_sizes, int n_in,
                              void* d_out, int out_size, void* d_ws, size_t ws_size,
                              hipStream_t stream)
{
    const float* hs  = (const float*)d_in[0];   // [8192][7168]
    const float* w   = (const float*)d_in[1];   // [7168][2112]
    const float* qw  = (const float*)d_in[2];   // [1536]
    const float* kvw = (const float*)d_in[3];   // [512]
    float* out = (float*)d_out;

    char* ws = (char*)d_ws;
    const size_t A_BYTES  = (size_t)M_DIM * K_DIM * 2;   // 117,440,512
    const size_t BT_BYTES = (size_t)N_PAD * K_DIM * 2;   //  31,195,136
    const size_t C_BYTES  = (size_t)M_DIM * N_PAD * 2;   //  35,651,584 each
    unsigned short* Abf = (unsigned short*)ws;
    unsigned short* Bt  = (unsigned short*)(ws + A_BYTES);
    unsigned short* C   = (unsigned short*)(ws + A_BYTES + BT_BYTES);
    unsigned short* C0  = C;
    unsigned short* C1  = C + (size_t)M_DIM * N_PAD;

    // 1) A fp32 -> bf16
    cvt_a_kernel<<<8192, 256, 0, stream>>>(hs, Abf, (M_DIM * K_DIM) / 4);

    // 2) W -> Bt (transpose + convert)
    dim3 gt(N_DIM / 32, K_DIM / 64);
    cvt_bt_kernel<<<gt, 256, 0, stream>>>(w, Bt);

    // 3) GEMM, split-K=2  (x = M tiles fastest for XCD-local A reuse)
    dim3 gg(M_DIM / TM, N_PAD / TN, SPLITK);   // (64, 17, 2)
    gemm_bf16_kernel<<<gg, 256, 0, stream>>>(Abf, Bt, C);

    // 4) epilogue
    epilogue_kernel<<<M_DIM, 256, 0, stream>>>(C0, C1, qw, kvw, out);
}